// Round 7
// baseline (89.051 us; speedup 1.0000x reference)
//
#include <hip/hip_runtime.h>
#include <hip/hip_fp16.h>

#define D 50
#define HIDDEN 32
#define NPN 32   // nodes per wave in node_proj

// ---------------------------------------------------------------------------
// Kernel 1: per-node projections -> fp16 table P[n][64]
//   P[n][j]    = sum_k z[n][k] * W1[k][j]      + b1[j]   (cols 0..31, src half)
//   P[n][32+j] = sum_k z[n][k] * W1[50+k][j]             (cols 32..63, dst half)
//
// The z-row broadcast is done on the VALU (4 pipes/CU) instead of the LDS or
// SMEM pipes (1 per CU, shared by all resident waves -- both measured ~25 us
// as the per-CU serialization floor). One coalesced vector load puts z[n][k]
// in lane k; 50x v_readlane (compile-time lane index) feeds v_fmac via the
// SGPR operand. Lane c owns output column c; its 50 W1 values stay in VGPRs.
// ---------------------------------------------------------------------------
__device__ __forceinline__ float proj_dot(float zv, const float* Breg, float bias) {
    float acc = bias;
#pragma unroll
    for (int k = 0; k < D; ++k) {
        float zk = __uint_as_float(
            (unsigned)__builtin_amdgcn_readlane((int)__float_as_uint(zv), k));
        acc = fmaf(zk, Breg[k], acc);
    }
    return acc;
}

__device__ __forceinline__ void store_row(__half2* __restrict__ P2, int n,
                                          int lane, float acc) {
    float nb = __shfl_xor(acc, 1);
    if ((lane & 1) == 0) {
        P2[(size_t)n * 32 + (lane >> 1)] = __floats2half2_rn(acc, nb);
    }
}

__global__ __launch_bounds__(256, 4) void node_proj_kernel(
        const float* __restrict__ z,
        const float* __restrict__ W1,
        const float* __restrict__ b1,
        __half2* __restrict__ P2,      // P viewed as half2[n_nodes][32]
        int n_nodes) {
    const int lane = threadIdx.x & 63;
    const int wid  = (blockIdx.x * blockDim.x + threadIdx.x) >> 6;

    int n0 = wid * NPN;                      // wave-uniform
    if (n0 >= n_nodes) return;
    int nend = n0 + NPN;
    if (nend > n_nodes) nend = n_nodes;

    const int j    = lane & 31;
    const int half = lane >> 5;

    // Per-lane W1 column in registers (coalesced: one 128B row per k).
    float Breg[D];
    const float* wcol = W1 + (size_t)(half * D) * HIDDEN + j;
#pragma unroll
    for (int k = 0; k < D; ++k) Breg[k] = wcol[(size_t)k * HIDDEN];

    const float bias = half ? 0.0f : b1[j];
    const bool  ld   = (lane < D);

    // Batches of 4 nodes: 4 coalesced row-loads in flight, then 4 dot chains.
    for (int n = n0; n < nend; n += 4) {
        int rem = nend - n;
        float zv0 = ld            ? z[(size_t)n * D + lane]       : 0.0f;
        float zv1 = (ld && rem > 1) ? z[(size_t)(n + 1) * D + lane] : 0.0f;
        float zv2 = (ld && rem > 2) ? z[(size_t)(n + 2) * D + lane] : 0.0f;
        float zv3 = (ld && rem > 3) ? z[(size_t)(n + 3) * D + lane] : 0.0f;

        store_row(P2, n, lane, proj_dot(zv0, Breg, bias));
        if (rem > 1) store_row(P2, n + 1, lane, proj_dot(zv1, Breg, bias));
        if (rem > 2) store_row(P2, n + 2, lane, proj_dot(zv2, Breg, bias));
        if (rem > 3) store_row(P2, n + 3, lane, proj_dot(zv3, Breg, bias));
    }
}

// ---------------------------------------------------------------------------
// Kernel 2: per-edge fused add + relu + dot(W2) + b2 -- 4 lanes per edge
// (round-5 proven form: 52 us, byte-bound on the random-gather fabric path).
// Lane r handles hidden units [8r, 8r+8): one 16B src chunk + one 16B dst
// chunk; lanes 0..3 read consecutive 16B -> one 64B segment per edge-side.
// Group-sum via shfl_xor(1,2); lane r==0 writes.
// ---------------------------------------------------------------------------
__global__ void edge_mlp_kernel(const int* __restrict__ eidx,
                                const __half* __restrict__ P,
                                const float* __restrict__ W2,
                                const float* __restrict__ b2,
                                float* __restrict__ out,
                                int n_edges) {
    int t = blockIdx.x * blockDim.x + threadIdx.x;
    int e = t >> 2;
    int r = t & 3;
    if (e >= n_edges) return;

    int s = eidx[e];
    int d = eidx[n_edges + e];

    uint4 ua = *(const uint4*)(P + (size_t)s * 64 + r * 8);        // src units 8r..8r+7
    uint4 ub = *(const uint4*)(P + (size_t)d * 64 + 32 + r * 8);   // dst units 8r..8r+7
    float4 w0 = *(const float4*)(W2 + r * 8);
    float4 w1 = *(const float4*)(W2 + r * 8 + 4);

    float2 a0 = __half22float2(*(const __half2*)&ua.x);
    float2 a1 = __half22float2(*(const __half2*)&ua.y);
    float2 a2 = __half22float2(*(const __half2*)&ua.z);
    float2 a3 = __half22float2(*(const __half2*)&ua.w);
    float2 b0 = __half22float2(*(const __half2*)&ub.x);
    float2 b1v = __half22float2(*(const __half2*)&ub.y);
    float2 b2v = __half22float2(*(const __half2*)&ub.z);
    float2 b3 = __half22float2(*(const __half2*)&ub.w);

    float acc = (r == 0) ? b2[0] : 0.0f;
    acc = fmaf(fmaxf(a0.x + b0.x,  0.0f), w0.x, acc);
    acc = fmaf(fmaxf(a0.y + b0.y,  0.0f), w0.y, acc);
    acc = fmaf(fmaxf(a1.x + b1v.x, 0.0f), w0.z, acc);
    acc = fmaf(fmaxf(a1.y + b1v.y, 0.0f), w0.w, acc);
    acc = fmaf(fmaxf(a2.x + b2v.x, 0.0f), w1.x, acc);
    acc = fmaf(fmaxf(a2.y + b2v.y, 0.0f), w1.y, acc);
    acc = fmaf(fmaxf(a3.x + b3.x,  0.0f), w1.z, acc);
    acc = fmaf(fmaxf(a3.y + b3.y,  0.0f), w1.w, acc);

    acc += __shfl_xor(acc, 1);
    acc += __shfl_xor(acc, 2);

    if (r == 0) out[e] = acc;
}

// ---------------------------------------------------------------------------
// Fallback (ws too small): direct per-edge full MLP. Slow but correct.
// ---------------------------------------------------------------------------
__global__ void edge_direct_kernel(const float* __restrict__ z,
                                   const int* __restrict__ eidx,
                                   const float* __restrict__ W1,
                                   const float* __restrict__ b1,
                                   const float* __restrict__ W2,
                                   const float* __restrict__ b2,
                                   float* __restrict__ out,
                                   int n_edges) {
    int e = blockIdx.x * blockDim.x + threadIdx.x;
    if (e >= n_edges) return;
    int s = eidx[e];
    int d = eidx[n_edges + e];
    const float* zs = z + (size_t)s * D;
    const float* zd = z + (size_t)d * D;
    float acc = b2[0];
    for (int j = 0; j < HIDDEN; ++j) {
        float h = b1[j];
        for (int k = 0; k < D; ++k) {
            h = fmaf(zs[k], W1[(size_t)k * HIDDEN + j], h);
            h = fmaf(zd[k], W1[(size_t)(D + k) * HIDDEN + j], h);
        }
        acc = fmaf(fmaxf(h, 0.0f), W2[j], acc);
    }
    out[e] = acc;
}

extern "C" void kernel_launch(void* const* d_in, const int* in_sizes, int n_in,
                              void* d_out, int out_size, void* d_ws, size_t ws_size,
                              hipStream_t stream) {
    const float* z    = (const float*)d_in[0];
    const int*   eidx = (const int*)d_in[1];
    const float* W1   = (const float*)d_in[2];
    const float* b1   = (const float*)d_in[3];
    const float* W2   = (const float*)d_in[4];
    const float* b2   = (const float*)d_in[5];
    float*       out  = (float*)d_out;

    const int n_nodes = in_sizes[0] / D;          // 100000
    const int n_edges = in_sizes[1] / 2;          // 2000000

    const size_t p_bytes = (size_t)n_nodes * 64 * sizeof(__half);

    if (p_bytes <= ws_size) {
        __half* P = (__half*)d_ws;

        // Kernel 1: one wave per NPN nodes, readlane z-broadcast.
        int n_waves = (n_nodes + NPN - 1) / NPN;
        int blocks1 = (n_waves * 64 + 255) / 256;
        node_proj_kernel<<<blocks1, 256, 0, stream>>>(z, W1, b1, (__half2*)P,
                                                      n_nodes);

        // Kernel 2: 4 threads per edge.
        long long total2 = (long long)n_edges * 4;
        int blocks2 = (int)((total2 + 255) / 256);
        edge_mlp_kernel<<<blocks2, 256, 0, stream>>>(eidx, P, W2, b2, out, n_edges);
    } else {
        int blocks = (n_edges + 255) / 256;
        edge_direct_kernel<<<blocks, 256, 0, stream>>>(z, eidx, W1, b1, W2, b2,
                                                       out, n_edges);
    }
}